// Round 5
// baseline (535.291 us; speedup 1.0000x reference)
//
#include <hip/hip_runtime.h>
#include <hip/hip_bf16.h>
#include <math.h>

// Problem constants
#define B_    8
#define C_    64
#define H_    64
#define W_    64
#define NUM_EMBED 8192
#define DIMS  64
#define N_TOK (B_ * H_ * W_)           // 32768
#define N_ELEM (B_ * C_ * H_ * W_)     // 2097152

typedef short v8s __attribute__((ext_vector_type(8)));   // 8 bf16 = 4 VGPR
typedef float v4f __attribute__((ext_vector_type(4)));   // MFMA acc

#define MARGIN 0.0095f  // rigorous bf16 bound 2*2^-8 = 0.0078, + headroom

// ---- helpers ---------------------------------------------------------------
__device__ __forceinline__ short bf16_rne(float x) {
    unsigned u = __float_as_uint(x);
    unsigned r = (u + 0x7FFFu + ((u >> 16) & 1u)) >> 16;
    return (short)r;
}
// monotone float->u32 (order-preserving, incl. negatives)
__device__ __forceinline__ unsigned mono(float f) {
    int b = __float_as_int(f);
    return (unsigned)(b ^ ((b >> 31) | 0x80000000));
}
__device__ __forceinline__ float demono(unsigned u) {
    int b = (u >> 31) ? (int)(u ^ 0x80000000u) : (int)~u;
    return __int_as_float(b);
}

// async global->LDS, 16B per lane; LDS dest = wave-uniform base + lane*16
__device__ __forceinline__ void gll16(const void* g, void* l) {
    __builtin_amdgcn_global_load_lds(
        (const __attribute__((address_space(1))) unsigned*)g,
        (__attribute__((address_space(3))) unsigned*)l, 16, 0, 0);
}

// ---------------------------------------------------------------------------
// P1: inverse row norms of embedding. 4 rows/block, one wave per row.
// ---------------------------------------------------------------------------
__global__ void invnorm_kernel(const float* __restrict__ emb, float* __restrict__ invn) {
    int wave = threadIdx.x >> 6;
    int lane = threadIdx.x & 63;
    int row  = blockIdx.x * 4 + wave;
    float v = emb[row * DIMS + lane];
    float s = v * v;
    #pragma unroll
    for (int off = 1; off < 64; off <<= 1) s += __shfl_xor(s, off, 64);
    if (lane == 0) invn[row] = 1.0f / sqrtf(s);
}

// ---------------------------------------------------------------------------
// P2: build B fragments: en_frag[(ct*2+st)*64 + lane] = 8 bf16 of
//     en[code = ct*16 + (lane&15)][k = st*32 + (lane>>4)*8 + j]
// (layout HW-verified by R2-R4 passes — keep byte-identical)
// ---------------------------------------------------------------------------
__global__ void en_frag_kernel(const float* __restrict__ emb, const float* __restrict__ invn,
                               v8s* __restrict__ ef) {
    int ch = blockIdx.x * 256 + threadIdx.x;      // 0..65535
    int l  = ch & 63;
    int st = (ch >> 6) & 1;
    int ct = ch >> 7;
    int code = ct * 16 + (l & 15);
    int kb   = st * 32 + ((l >> 4) & 3) * 8;
    float rn = invn[code];
    v8s o;
    #pragma unroll
    for (int j = 0; j < 8; ++j) o[j] = bf16_rne(emb[code * DIMS + kb + j] * rn);
    ef[ch] = o;
}

// ---------------------------------------------------------------------------
// P3: z -> z_tok (fp32 token-major, for exact rescore)  +  A fragments.
// ---------------------------------------------------------------------------
__global__ __launch_bounds__(256)
void z_prep_kernel(const float* __restrict__ z, float* __restrict__ z_tok,
                   v8s* __restrict__ af) {
    __shared__ float zs[64][65];   // [c][token_local], +1 pad
    __shared__ float part[4][64];
    __shared__ float rn[64];
    const int tid = threadIdx.x;
    const int w   = tid & 63;
    const int cg  = tid >> 6;
    const int bh  = blockIdx.x;            // 0..511
    const int b   = bh >> 6, h = bh & 63;

    const float* zb = z + (size_t)b * (C_ * H_ * W_) + h * W_;
    float ss = 0.f;
    #pragma unroll
    for (int cc = 0; cc < 16; ++cc) {
        int c = cg * 16 + cc;
        float v = zb[c * (H_ * W_) + w];
        zs[c][w] = v;
        ss += v * v;
    }
    part[cg][w] = ss;
    __syncthreads();
    if (tid < 64) {
        float s = part[0][tid] + part[1][tid] + part[2][tid] + part[3][tid];
        rn[tid] = 1.0f / sqrtf(s);
    }
    __syncthreads();

    // z_tok[t][c], coalesced in c
    {
        int c  = tid & 63;
        int tg = tid >> 6;
        #pragma unroll
        for (int i = 0; i < 16; ++i) {
            int tloc = tg * 16 + i;
            z_tok[(size_t)(bh * 64 + tloc) * DIMS + c] = zs[c][tloc];
        }
    }
    // A fragments
    #pragma unroll
    for (int ii = 0; ii < 2; ++ii) {
        int ch  = tid + ii * 256;
        int mtl = ch >> 7;
        int st  = (ch >> 6) & 1;
        int l   = ch & 63;
        int tloc = mtl * 16 + (l & 15);
        int kb   = st * 32 + ((l >> 4) & 3) * 8;
        float rr = rn[tloc];
        v8s o;
        #pragma unroll
        for (int j = 0; j < 8; ++j) o[j] = bf16_rne(zs[kb + j][tloc] * rr);
        af[(size_t)((bh * 4 + mtl) * 2 + st) * 64 + l] = o;
    }
}

// ---------------------------------------------------------------------------
// pass1f: single sequential-scan fused GEMM + atomic-free candidate append.
//  256 thr (4 waves), RT=2 m-tiles/wave -> 128 tokens/block, grid 256 (1/CU).
//  Each block scans ALL 8192 codes: 32 chunks of 256 codes, 2x32KB LDS dbuf.
//  Chunk 0 warm (max only), re-scanned at end vs final threshold.
//  Token ownership is exclusive to one wave -> slot assignment by ballot
//  prefix within the 16-lane quad group; cnt/tokmax are plain stores.
// ---------------------------------------------------------------------------
#define RT 2
#define CHUNK_TILES 16
#define NCHUNKS (NUM_EMBED / 16 / CHUNK_TILES)      // 32
#define CHUNK_BYTES (CHUNK_TILES * 2 * 64 * 16)     // 32768

__device__ __forceinline__ void stage_chunk(const char* g, char* l, int wave, int lane) {
    #pragma unroll
    for (int i = 0; i < 8; ++i) {
        int unit = wave * 8 + i;
        gll16(g + unit * 1024 + lane * 16, l + unit * 1024);
    }
}

__global__ __launch_bounds__(256, 2)
void pass1f_kernel(const v8s* __restrict__ af, const v8s* __restrict__ ef,
                   unsigned* __restrict__ tokmax, unsigned* __restrict__ cnt,
                   unsigned long long* __restrict__ cand, int slots) {
    __shared__ v8s lds[2][CHUNK_TILES * 2 * 64];   // 2 x 32 KB
    const int tid  = threadIdx.x;
    const int lane = tid & 63;
    const int wave = tid >> 6;
    const int quad = lane >> 4;
    const int col  = lane & 15;
    const int mtb  = blockIdx.x * 8 + wave * RT;   // first m-tile of this wave

    v8s a[RT][2];
    #pragma unroll
    for (int r = 0; r < RT; ++r)
        #pragma unroll
        for (int s = 0; s < 2; ++s)
            a[r][s] = af[(size_t)((mtb + r) * 2 + s) * 64 + lane];

    float mx[RT][4], thr[RT][4];
    int cnt_reg[RT][4];
    #pragma unroll
    for (int r = 0; r < RT; ++r)
        #pragma unroll
        for (int i = 0; i < 4; ++i) { mx[r][i] = -1e30f; thr[r][i] = 1e30f; cnt_reg[r][i] = 0; }

    const char* gbase = (const char*)ef;
    stage_chunk(gbase, (char*)lds[0], wave, lane);

    // process one chunk's 16 tiles; APPEND folded at 3 inlined call sites
    auto process = [&](const v8s* buf, int ctile, bool append) {
        #pragma unroll 2
        for (int j = 0; j < CHUNK_TILES; ++j) {
            v8s b0 = buf[(j * 2 + 0) * 64 + lane];
            v8s b1 = buf[(j * 2 + 1) * 64 + lane];
            v4f acc[RT];
            #pragma unroll
            for (int r = 0; r < RT; ++r) {
                v4f t = (v4f){0.f, 0.f, 0.f, 0.f};
                t = __builtin_amdgcn_mfma_f32_16x16x32_bf16(a[r][0], b0, t, 0, 0, 0);
                t = __builtin_amdgcn_mfma_f32_16x16x32_bf16(a[r][1], b1, t, 0, 0, 0);
                acc[r] = t;
            }
            #pragma unroll
            for (int r = 0; r < RT; ++r)
                #pragma unroll
                for (int i = 0; i < 4; ++i) {
                    float v = acc[r][i];
                    if (append) {
                        bool cond = (v >= thr[r][i]);
                        unsigned long long m = __ballot(cond);
                        if (m) {                     // rare (~5 appends/token total)
                            unsigned qm  = (unsigned)((m >> (quad * 16)) & 0xFFFFull);
                            int base = cnt_reg[r][i];
                            cnt_reg[r][i] = base + __popc(qm);   // quad-consistent
                            if (cond) {
                                int slot = base + __popc(qm & ((1u << col) - 1u));
                                if (slot < slots) {
                                    int tok  = (mtb + r) * 16 + quad * 4 + i;
                                    int code = (ctile + j) * 16 + col;
                                    cand[(size_t)tok * slots + slot] =
                                        ((unsigned long long)mono(v) << 32) | (unsigned)code;
                                }
                            }
                        }
                    }
                    mx[r][i] = fmaxf(mx[r][i], v);
                }
        }
    };

    for (int c = 0; c < NCHUNKS; ++c) {
        __syncthreads();    // drains this wave's outstanding global_load_lds
        if (c + 1 < NCHUNKS)
            stage_chunk(gbase + (size_t)(c + 1) * CHUNK_BYTES,
                        (char*)lds[(c + 1) & 1], wave, lane);
        process(lds[c & 1], c * CHUNK_TILES, c > 0);   // chunk 0 warm: max only
        // cross-column (16 code-cols) running max -> threshold for next chunk
        #pragma unroll
        for (int r = 0; r < RT; ++r)
            #pragma unroll
            for (int i = 0; i < 4; ++i) {
                float v = mx[r][i];
                v = fmaxf(v, __shfl_xor(v, 1, 64));
                v = fmaxf(v, __shfl_xor(v, 2, 64));
                v = fmaxf(v, __shfl_xor(v, 4, 64));
                v = fmaxf(v, __shfl_xor(v, 8, 64));
                mx[r][i]  = v;
                thr[r][i] = v - MARGIN;
            }
    }

    // re-scan chunk 0 (was warm) against the final threshold
    __syncthreads();
    stage_chunk(gbase, (char*)lds[0], wave, lane);
    __syncthreads();
    process(lds[0], 0, true);

    // publish per-token exact bf16 max + candidate count (no atomics needed)
    if (col == 0) {
        #pragma unroll
        for (int r = 0; r < RT; ++r)
            #pragma unroll
            for (int i = 0; i < 4; ++i) {
                int tok = (mtb + r) * 16 + quad * 4 + i;
                tokmax[tok] = mono(mx[r][i]);
                cnt[tok]    = (unsigned)cnt_reg[r][i];
            }
    }
}

// ---------------------------------------------------------------------------
// filter: one wave per token: keep cands >= tokmax - MARGIN, exact fp32
// rescore (R2-R4-proven shuffle-tree formula), write idx + idxmap directly.
// Overflowed tokens deferred to fallback.
// ---------------------------------------------------------------------------
__global__ __launch_bounds__(256)
void filter_kernel(const unsigned long long* __restrict__ cand,
                   const unsigned* __restrict__ cnt, const unsigned* __restrict__ tokmax,
                   const float* __restrict__ z_tok, const float* __restrict__ emb,
                   const float* __restrict__ invn, int slots,
                   int* __restrict__ idx, float* __restrict__ idxmap,
                   int* __restrict__ ovflist, unsigned* __restrict__ ovfcnt) {
    const int lane = threadIdx.x & 63;
    const int wid  = blockIdx.x * 4 + (threadIdx.x >> 6);   // 0..4095
    for (int k = 0; k < 8; ++k) {
        const int t = wid * 8 + k;
        unsigned c = cnt[t];
        if (c > (unsigned)slots) {
            if (lane == 0) { unsigned s = atomicAdd(ovfcnt, 1u); ovflist[s] = t; }
            continue;
        }
        float thrf = demono(tokmax[t]) - MARGIN;
        float zv = z_tok[(size_t)t * DIMS + lane];
        unsigned long long best = 0;
        for (unsigned s = 0; s < c; ++s) {
            unsigned long long e = cand[(size_t)t * slots + s];
            if (demono((unsigned)(e >> 32)) < thrf) continue;
            int code = (int)(e & 0xFFFFFFFFull);
            float p = zv * emb[(size_t)code * DIMS + lane];
            #pragma unroll
            for (int o = 32; o; o >>= 1) p += __shfl_xor(p, o, 64);
            float d = p * invn[code];
            unsigned long long pk = ((unsigned long long)mono(d) << 32) |
                                    (0xFFFFFFFFu - (unsigned)code);
            if (pk > best) best = pk;
        }
        if (lane == 0) {
            unsigned code = 0xFFFFFFFFu - (unsigned)(best & 0xFFFFFFFFull);
            idx[t] = (int)code;
            idxmap[t] = (float)code;
        }
    }
}

// ---------------------------------------------------------------------------
// fallback: exact brute force for overflow tokens (expected zero work).
// ---------------------------------------------------------------------------
__global__ __launch_bounds__(256)
void fallback_kernel(const int* __restrict__ ovflist, const unsigned* __restrict__ ovfcnt,
                     const float* __restrict__ z_tok, const float* __restrict__ emb,
                     const float* __restrict__ invn,
                     unsigned long long* __restrict__ winner) {
    __shared__ unsigned long long red[4];
    const int lane = threadIdx.x & 63;
    const int wave = threadIdx.x >> 6;
    const int nt = (int)*ovfcnt;
    const int units = nt * 4;
    for (int u = blockIdx.x; u < units; u += gridDim.x) {
        const int t = ovflist[u >> 2];
        const int q = u & 3;
        float zv = z_tok[(size_t)t * DIMS + lane];
        unsigned long long best = 0;
        for (int code = q * 2048 + wave; code < (q + 1) * 2048; code += 4) {
            float p = zv * emb[(size_t)code * DIMS + lane];
            #pragma unroll
            for (int o = 32; o; o >>= 1) p += __shfl_xor(p, o, 64);
            float d = p * invn[code];
            unsigned long long pk = ((unsigned long long)mono(d) << 32) |
                                    (0xFFFFFFFFu - (unsigned)code);
            if (pk > best) best = pk;
        }
        if (lane == 0) red[wave] = best;
        __syncthreads();
        if (threadIdx.x == 0) {
            unsigned long long m = red[0];
            if (red[1] > m) m = red[1];
            if (red[2] > m) m = red[2];
            if (red[3] > m) m = red[3];
            atomicMax(&winner[t], m);
        }
        __syncthreads();
    }
}

__global__ void fallback_fin_kernel(const int* __restrict__ ovflist,
                                    const unsigned* __restrict__ ovfcnt,
                                    const unsigned long long* __restrict__ winner,
                                    int* __restrict__ idx, float* __restrict__ idxmap) {
    int nt = (int)*ovfcnt;
    int i = blockIdx.x * 256 + threadIdx.x;
    if (i < nt) {
        int t = ovflist[i];
        unsigned code = 0xFFFFFFFFu - (unsigned)(winner[t] & 0xFFFFFFFFull);
        idx[t] = (int)code;
        idxmap[t] = (float)code;
    }
}

// ---------------------------------------------------------------------------
// K3: gather z_q, out = zv + (q - zv), SSE partial, histogram.
// ---------------------------------------------------------------------------
__global__ void gather_loss_kernel(const float* __restrict__ z,
                                   const float* __restrict__ emb,
                                   const int* __restrict__ idx,
                                   float* __restrict__ out,
                                   float* __restrict__ partial,
                                   int* __restrict__ hist) {
    __shared__ float red[256];
    const int tid  = threadIdx.x;
    const int lane = tid & 63;   // w
    const int wave = tid >> 6;
    const int bt   = blockIdx.x; // 0..511
    const int b    = bt >> 6;
    const int h    = bt & 63;

    const int t  = bt * 64 + lane;
    const int id = idx[t];
    const long base = (long)b * (C_ * H_ * W_) + h * W_ + lane;

    float sse = 0.f;
    #pragma unroll
    for (int cc = 0; cc < 16; ++cc) {
        const int c = wave * 16 + cc;
        const float q  = emb[id * DIMS + c];
        const float zv = z[base + (long)c * (H_ * W_)];
        out[base + (long)c * (H_ * W_)] = zv + (q - zv);  // exact ref expression
        const float d = q - zv;
        sse += d * d;
    }

    red[tid] = sse;
    __syncthreads();
    for (int s = 128; s > 0; s >>= 1) {
        if (tid < s) red[tid] += red[tid + s];
        __syncthreads();
    }
    if (tid == 0) partial[bt] = red[0];
    if (wave == 0) atomicAdd(&hist[id], 1);
}

// ---------------------------------------------------------------------------
// K4: finalize loss + perplexity. One block of 256 threads.
// ---------------------------------------------------------------------------
__global__ void finalize_kernel(const float* __restrict__ partial,
                                const int* __restrict__ hist,
                                float* __restrict__ out_scal) {
    __shared__ double red[256];
    const int tid = threadIdx.x;

    double s = 0.0;
    for (int i = tid; i < 512; i += 256) s += (double)partial[i];
    red[tid] = s;
    __syncthreads();
    for (int st = 128; st > 0; st >>= 1) {
        if (tid < st) red[tid] += red[tid + st];
        __syncthreads();
    }
    const double sse = red[0];
    __syncthreads();

    double e = 0.0;
    for (int k = tid; k < NUM_EMBED; k += 256) {
        float p = (float)hist[k] / (float)N_TOK;
        e += (double)(p * logf(p + 1e-10f));
    }
    red[tid] = e;
    __syncthreads();
    for (int st = 128; st > 0; st >>= 1) {
        if (tid < st) red[tid] += red[tid + st];
        __syncthreads();
    }
    if (tid == 0) {
        out_scal[0] = (float)(1.25 * sse / (double)N_ELEM);
        out_scal[1] = expf(-(float)red[0]);
    }
}

// ---------------------------------------------------------------------------
extern "C" void kernel_launch(void* const* d_in, const int* in_sizes, int n_in,
                              void* d_out, int out_size, void* d_ws, size_t ws_size,
                              hipStream_t stream) {
    const float* z   = (const float*)d_in[0];
    const float* emb = (const float*)d_in[1];
    float* o = (float*)d_out;

    // workspace layout (static 6.1 MB; cand sized from ws_size)
    char* ws = (char*)d_ws;
    v8s*  af      = (v8s*)ws;                                        // 4 MB
    v8s*  ef      = (v8s*)(ws + 4194304);                            // 1 MB
    unsigned* tokmax = (unsigned*)(ws + 5242880);                    // 128 KB
    unsigned* cnt    = (unsigned*)(ws + 5373952);                    // 128 KB
    int*   idx     = (int*)(ws + 5505024);                           // 128 KB
    float* invn    = (float*)(ws + 5636096);                         // 32 KB
    float* partial = (float*)(ws + 5668864);                         // 4 KB
    // ---- zeroed region: hist | ovfcnt | winner (contiguous) ----
    int*   hist    = (int*)(ws + 5672960);                           // 32 KB
    unsigned* ovfcnt = (unsigned*)(ws + 5705728);                    // 256 B
    unsigned long long* winner = (unsigned long long*)(ws + 5705984);// 256 KB
    int*   ovflist = (int*)(ws + 5968128);                           // 128 KB
    unsigned long long* cand = (unsigned long long*)(ws + 6099200);

    // candidate slots per token, bounded by remaining workspace (cap 24;
    // expected appends ~5/token with global-prefix thresholds)
    long long avail = (long long)ws_size - 6099200;
    int slots = (int)(avail / ((long long)N_TOK * 8));
    if (slots > 24) slots = 24;
    if (slots < 0)  slots = 0;

    float* out_q      = o;                  // 2097152 floats
    float* out_scal   = o + N_ELEM;         // loss, perplexity
    float* out_idxmap = o + N_ELEM + 2;     // 32768 floats
    float* z_tok      = o;                  // out_q region reused as fp32 token-major
                                            // scratch; overwritten by gather later

    hipMemsetAsync(hist, 0, 5968128 - 5672960, stream);  // hist|ovfcnt|winner

    invnorm_kernel<<<NUM_EMBED / 4, 256, 0, stream>>>(emb, invn);
    en_frag_kernel<<<256, 256, 0, stream>>>(emb, invn, ef);
    z_prep_kernel<<<512, 256, 0, stream>>>(z, z_tok, af);
    pass1f_kernel<<<256, 256, 0, stream>>>(af, ef, tokmax, cnt, cand, slots);
    filter_kernel<<<1024, 256, 0, stream>>>(cand, cnt, tokmax, z_tok, emb, invn,
                                            slots, idx, out_idxmap, ovflist, ovfcnt);
    fallback_kernel<<<512, 256, 0, stream>>>(ovflist, ovfcnt, z_tok, emb, invn, winner);
    fallback_fin_kernel<<<128, 256, 0, stream>>>(ovflist, ovfcnt, winner, idx, out_idxmap);
    gather_loss_kernel<<<N_TOK / 64, 256, 0, stream>>>(z, emb, idx, out_q, partial, hist);
    finalize_kernel<<<1, 256, 0, stream>>>(partial, hist, out_scal);
}

// Round 6
// 290.005 us; speedup vs baseline: 1.8458x; 1.8458x over previous
//
#include <hip/hip_runtime.h>
#include <hip/hip_bf16.h>
#include <math.h>

// Problem constants
#define B_    8
#define C_    64
#define H_    64
#define W_    64
#define NUM_EMBED 8192
#define DIMS  64
#define N_TOK (B_ * H_ * W_)           // 32768
#define N_ELEM (B_ * C_ * H_ * W_)     // 2097152

typedef short v8s __attribute__((ext_vector_type(8)));   // 8 bf16 = 4 VGPR
typedef float v4f __attribute__((ext_vector_type(4)));   // MFMA acc

#define MARGIN 0.0095f  // rigorous bf16 bound 2*2^-8 = 0.0078, + headroom

// ---- helpers ---------------------------------------------------------------
__device__ __forceinline__ short bf16_rne(float x) {
    unsigned u = __float_as_uint(x);
    unsigned r = (u + 0x7FFFu + ((u >> 16) & 1u)) >> 16;
    return (short)r;
}
// monotone float->u32 (order-preserving, incl. negatives)
__device__ __forceinline__ unsigned mono(float f) {
    int b = __float_as_int(f);
    return (unsigned)(b ^ ((b >> 31) | 0x80000000));
}
__device__ __forceinline__ float demono(unsigned u) {
    int b = (u >> 31) ? (int)(u ^ 0x80000000u) : (int)~u;
    return __int_as_float(b);
}

// async global->LDS, 16B per lane; LDS dest = wave-uniform base + lane*16
__device__ __forceinline__ void gll16(const void* g, void* l) {
    __builtin_amdgcn_global_load_lds(
        (const __attribute__((address_space(1))) unsigned*)g,
        (__attribute__((address_space(3))) unsigned*)l, 16, 0, 0);
}

// ---------------------------------------------------------------------------
// P1: inverse row norms of embedding. 4 rows/block, one wave per row.
// ---------------------------------------------------------------------------
__global__ void invnorm_kernel(const float* __restrict__ emb, float* __restrict__ invn) {
    int wave = threadIdx.x >> 6;
    int lane = threadIdx.x & 63;
    int row  = blockIdx.x * 4 + wave;
    float v = emb[row * DIMS + lane];
    float s = v * v;
    #pragma unroll
    for (int off = 1; off < 64; off <<= 1) s += __shfl_xor(s, off, 64);
    if (lane == 0) invn[row] = 1.0f / sqrtf(s);
}

// ---------------------------------------------------------------------------
// P2: build B fragments: en_frag[(ct*2+st)*64 + lane] = 8 bf16 of
//     en[code = ct*16 + (lane&15)][k = st*32 + (lane>>4)*8 + j]
// (layout HW-verified by R2-R5 passes — keep byte-identical)
// ---------------------------------------------------------------------------
__global__ void en_frag_kernel(const float* __restrict__ emb, const float* __restrict__ invn,
                               v8s* __restrict__ ef) {
    int ch = blockIdx.x * 256 + threadIdx.x;      // 0..65535
    int l  = ch & 63;
    int st = (ch >> 6) & 1;
    int ct = ch >> 7;
    int code = ct * 16 + (l & 15);
    int kb   = st * 32 + ((l >> 4) & 3) * 8;
    float rn = invn[code];
    v8s o;
    #pragma unroll
    for (int j = 0; j < 8; ++j) o[j] = bf16_rne(emb[code * DIMS + kb + j] * rn);
    ef[ch] = o;
}

// ---------------------------------------------------------------------------
// P3: z -> z_tok (fp32 token-major, for exact rescore)  +  A fragments.
// ---------------------------------------------------------------------------
__global__ __launch_bounds__(256)
void z_prep_kernel(const float* __restrict__ z, float* __restrict__ z_tok,
                   v8s* __restrict__ af) {
    __shared__ float zs[64][65];   // [c][token_local], +1 pad
    __shared__ float part[4][64];
    __shared__ float rn[64];
    const int tid = threadIdx.x;
    const int w   = tid & 63;
    const int cg  = tid >> 6;
    const int bh  = blockIdx.x;            // 0..511
    const int b   = bh >> 6, h = bh & 63;

    const float* zb = z + (size_t)b * (C_ * H_ * W_) + h * W_;
    float ss = 0.f;
    #pragma unroll
    for (int cc = 0; cc < 16; ++cc) {
        int c = cg * 16 + cc;
        float v = zb[c * (H_ * W_) + w];
        zs[c][w] = v;
        ss += v * v;
    }
    part[cg][w] = ss;
    __syncthreads();
    if (tid < 64) {
        float s = part[0][tid] + part[1][tid] + part[2][tid] + part[3][tid];
        rn[tid] = 1.0f / sqrtf(s);
    }
    __syncthreads();

    // z_tok[t][c], coalesced in c
    {
        int c  = tid & 63;
        int tg = tid >> 6;
        #pragma unroll
        for (int i = 0; i < 16; ++i) {
            int tloc = tg * 16 + i;
            z_tok[(size_t)(bh * 64 + tloc) * DIMS + c] = zs[c][tloc];
        }
    }
    // A fragments
    #pragma unroll
    for (int ii = 0; ii < 2; ++ii) {
        int ch  = tid + ii * 256;
        int mtl = ch >> 7;
        int st  = (ch >> 6) & 1;
        int l   = ch & 63;
        int tloc = mtl * 16 + (l & 15);
        int kb   = st * 32 + ((l >> 4) & 3) * 8;
        float rr = rn[tloc];
        v8s o;
        #pragma unroll
        for (int j = 0; j < 8; ++j) o[j] = bf16_rne(zs[kb + j][tloc] * rr);
        af[(size_t)((bh * 4 + mtl) * 2 + st) * 64 + l] = o;
    }
}

// ---------------------------------------------------------------------------
// pass1f: sequential-scan fused GEMM + atomic-free candidate append.
//  256 thr (4 waves), 1 m-tile/wave -> 64 tokens/block, grid 512 (2/CU,
//  2 waves/SIMD). Each block scans ALL 8192 codes: 32 chunks of 256 codes,
//  2x32KB LDS dbuf via global_load_lds. Chunk 0 warm (max only), re-scanned
//  at end vs final threshold. Fast path = ONE ballot per j; per-slot ballots
//  only inside the rare wave-uniform branch. Slot assignment by quad-local
//  popcount prefix; cnt/tokmax are plain stores (token owned by one wave).
// ---------------------------------------------------------------------------
#define CHUNK_TILES 16
#define NCHUNKS (NUM_EMBED / 16 / CHUNK_TILES)      // 32
#define CHUNK_BYTES (CHUNK_TILES * 2 * 64 * 16)     // 32768

__device__ __forceinline__ void stage_chunk(const char* g, char* l, int wave, int lane) {
    #pragma unroll
    for (int i = 0; i < 8; ++i) {
        int unit = wave * 8 + i;
        gll16(g + unit * 1024 + lane * 16, l + unit * 1024);
    }
}

__global__ __launch_bounds__(256, 2)
void pass1f_kernel(const v8s* __restrict__ af, const v8s* __restrict__ ef,
                   unsigned* __restrict__ tokmax, unsigned* __restrict__ cnt,
                   unsigned long long* __restrict__ cand, int slots) {
    __shared__ v8s lds[2][CHUNK_TILES * 2 * 64];   // 2 x 32 KB
    const int tid  = threadIdx.x;
    const int lane = tid & 63;
    const int wave = tid >> 6;
    const int quad = lane >> 4;
    const int col  = lane & 15;
    const int mtile = blockIdx.x * 4 + wave;       // 0..2047

    v8s a0 = af[(size_t)(mtile * 2 + 0) * 64 + lane];
    v8s a1 = af[(size_t)(mtile * 2 + 1) * 64 + lane];

    float mx[4], thr[4];
    int cnt_reg[4];
    #pragma unroll
    for (int i = 0; i < 4; ++i) { mx[i] = -1e30f; thr[i] = 1e30f; cnt_reg[i] = 0; }

    const char* gbase = (const char*)ef;
    stage_chunk(gbase, (char*)lds[0], wave, lane);

    // process one chunk's 16 tiles
    auto process = [&](const v8s* buf, int ctile, bool append) {
        #pragma unroll 4
        for (int j = 0; j < CHUNK_TILES; ++j) {
            v8s b0 = buf[(j * 2 + 0) * 64 + lane];
            v8s b1 = buf[(j * 2 + 1) * 64 + lane];
            v4f t = (v4f){0.f, 0.f, 0.f, 0.f};
            t = __builtin_amdgcn_mfma_f32_16x16x32_bf16(a0, b0, t, 0, 0, 0);
            t = __builtin_amdgcn_mfma_f32_16x16x32_bf16(a1, b1, t, 0, 0, 0);
            if (append) {
                unsigned pm = 0;
                #pragma unroll
                for (int i = 0; i < 4; ++i)
                    pm |= (t[i] >= thr[i]) ? (1u << i) : 0u;
                if (__ballot(pm != 0)) {             // ONE ballot; rare branch
                    #pragma unroll
                    for (int i = 0; i < 4; ++i) {
                        unsigned long long m = __ballot((pm >> i) & 1);
                        if (m) {
                            unsigned qm = (unsigned)((m >> (quad * 16)) & 0xFFFFull);
                            int base = cnt_reg[i];
                            cnt_reg[i] = base + __popc(qm);   // quad-consistent
                            if ((pm >> i) & 1) {
                                int slot = base + __popc(qm & ((1u << col) - 1u));
                                if (slot < slots) {
                                    int tok  = mtile * 16 + quad * 4 + i;
                                    int code = (ctile + j) * 16 + col;
                                    cand[(size_t)tok * slots + slot] =
                                        ((unsigned long long)mono(t[i]) << 32) | (unsigned)code;
                                }
                            }
                        }
                    }
                }
            }
            #pragma unroll
            for (int i = 0; i < 4; ++i) mx[i] = fmaxf(mx[i], t[i]);
        }
    };

    for (int c = 0; c < NCHUNKS; ++c) {
        __syncthreads();    // drains this wave's outstanding global_load_lds
        if (c + 1 < NCHUNKS)
            stage_chunk(gbase + (size_t)(c + 1) * CHUNK_BYTES,
                        (char*)lds[(c + 1) & 1], wave, lane);
        if (c == 0) process(lds[0], 0, false);          // warm: max only
        else        process(lds[c & 1], c * CHUNK_TILES, true);
        // cross-column (16 code-cols) running max -> threshold
        #pragma unroll
        for (int i = 0; i < 4; ++i) {
            float v = mx[i];
            v = fmaxf(v, __shfl_xor(v, 1, 64));
            v = fmaxf(v, __shfl_xor(v, 2, 64));
            v = fmaxf(v, __shfl_xor(v, 4, 64));
            v = fmaxf(v, __shfl_xor(v, 8, 64));
            mx[i]  = v;
            thr[i] = v - MARGIN;
        }
    }

    // re-scan chunk 0 (was warm) against the final threshold
    __syncthreads();
    stage_chunk(gbase, (char*)lds[0], wave, lane);
    __syncthreads();
    process(lds[0], 0, true);

    // publish per-token exact bf16 max + candidate count (no atomics)
    if (col == 0) {
        #pragma unroll
        for (int i = 0; i < 4; ++i) {
            int tok = mtile * 16 + quad * 4 + i;
            tokmax[tok] = mono(mx[i]);
            cnt[tok]    = (unsigned)cnt_reg[i];
        }
    }
}

// ---------------------------------------------------------------------------
// filter: one wave per token: keep cands >= tokmax - MARGIN, exact fp32
// rescore (R2-R5-proven shuffle-tree formula), write idx + idxmap directly.
// Overflowed tokens deferred to fallback.
// ---------------------------------------------------------------------------
__global__ __launch_bounds__(256)
void filter_kernel(const unsigned long long* __restrict__ cand,
                   const unsigned* __restrict__ cnt, const unsigned* __restrict__ tokmax,
                   const float* __restrict__ z_tok, const float* __restrict__ emb,
                   const float* __restrict__ invn, int slots,
                   int* __restrict__ idx, float* __restrict__ idxmap,
                   int* __restrict__ ovflist, unsigned* __restrict__ ovfcnt) {
    const int lane = threadIdx.x & 63;
    const int wid  = blockIdx.x * 4 + (threadIdx.x >> 6);   // 0..4095
    for (int k = 0; k < 8; ++k) {
        const int t = wid * 8 + k;
        unsigned c = cnt[t];
        if (c > (unsigned)slots) {
            if (lane == 0) { unsigned s = atomicAdd(ovfcnt, 1u); ovflist[s] = t; }
            continue;
        }
        float thrf = demono(tokmax[t]) - MARGIN;
        float zv = z_tok[(size_t)t * DIMS + lane];
        unsigned long long best = 0;
        for (unsigned s = 0; s < c; ++s) {
            unsigned long long e = cand[(size_t)t * slots + s];
            if (demono((unsigned)(e >> 32)) < thrf) continue;
            int code = (int)(e & 0xFFFFFFFFull);
            float p = zv * emb[(size_t)code * DIMS + lane];
            #pragma unroll
            for (int o = 32; o; o >>= 1) p += __shfl_xor(p, o, 64);
            float d = p * invn[code];
            unsigned long long pk = ((unsigned long long)mono(d) << 32) |
                                    (0xFFFFFFFFu - (unsigned)code);
            if (pk > best) best = pk;
        }
        if (lane == 0) {
            unsigned code = 0xFFFFFFFFu - (unsigned)(best & 0xFFFFFFFFull);
            idx[t] = (int)code;
            idxmap[t] = (float)code;
        }
    }
}

// ---------------------------------------------------------------------------
// fallback: exact brute force for overflow tokens — one BLOCK per token,
// 256 threads x 32 codes each (code-parallel, latency-hidden), float4 dot
// against LDS-cached z row, LDS tree-reduce of packed keys. Writes idx
// directly (block exclusively owns its token).
// ---------------------------------------------------------------------------
__global__ __launch_bounds__(256)
void fallback_kernel(const int* __restrict__ ovflist, const unsigned* __restrict__ ovfcnt,
                     const float* __restrict__ z_tok, const float* __restrict__ emb,
                     const float* __restrict__ invn,
                     int* __restrict__ idx, float* __restrict__ idxmap) {
    __shared__ float zsh[64];
    __shared__ unsigned long long red[256];
    const int tid = threadIdx.x;
    const int nt = (int)*ovfcnt;
    for (int u = blockIdx.x; u < nt; u += gridDim.x) {
        const int t = ovflist[u];
        if (tid < 64) zsh[tid] = z_tok[(size_t)t * DIMS + tid];
        __syncthreads();
        unsigned long long best = 0;
        for (int code = tid; code < NUM_EMBED; code += 256) {
            const float4* e4 = (const float4*)(emb + (size_t)code * DIMS);
            const float4* z4 = (const float4*)zsh;
            float s0 = 0.f, s1 = 0.f, s2 = 0.f, s3 = 0.f;
            #pragma unroll
            for (int q = 0; q < 16; ++q) {
                float4 e = e4[q]; float4 zz = z4[q];
                s0 += zz.x * e.x; s1 += zz.y * e.y;
                s2 += zz.z * e.z; s3 += zz.w * e.w;
            }
            float d = ((s0 + s1) + (s2 + s3)) * invn[code];
            unsigned long long pk = ((unsigned long long)mono(d) << 32) |
                                    (0xFFFFFFFFu - (unsigned)code);
            if (pk > best) best = pk;
        }
        red[tid] = best;
        __syncthreads();
        for (int s = 128; s > 0; s >>= 1) {
            if (tid < s && red[tid + s] > red[tid]) red[tid] = red[tid + s];
            __syncthreads();
        }
        if (tid == 0) {
            unsigned code = 0xFFFFFFFFu - (unsigned)(red[0] & 0xFFFFFFFFull);
            idx[t] = (int)code;
            idxmap[t] = (float)code;
        }
        __syncthreads();
    }
}

// ---------------------------------------------------------------------------
// K3: gather z_q, out = zv + (q - zv), SSE partial, histogram.
// ---------------------------------------------------------------------------
__global__ void gather_loss_kernel(const float* __restrict__ z,
                                   const float* __restrict__ emb,
                                   const int* __restrict__ idx,
                                   float* __restrict__ out,
                                   float* __restrict__ partial,
                                   int* __restrict__ hist) {
    __shared__ float red[256];
    const int tid  = threadIdx.x;
    const int lane = tid & 63;   // w
    const int wave = tid >> 6;
    const int bt   = blockIdx.x; // 0..511
    const int b    = bt >> 6;
    const int h    = bt & 63;

    const int t  = bt * 64 + lane;
    const int id = idx[t];
    const long base = (long)b * (C_ * H_ * W_) + h * W_ + lane;

    float sse = 0.f;
    #pragma unroll
    for (int cc = 0; cc < 16; ++cc) {
        const int c = wave * 16 + cc;
        const float q  = emb[id * DIMS + c];
        const float zv = z[base + (long)c * (H_ * W_)];
        out[base + (long)c * (H_ * W_)] = zv + (q - zv);  // exact ref expression
        const float d = q - zv;
        sse += d * d;
    }

    red[tid] = sse;
    __syncthreads();
    for (int s = 128; s > 0; s >>= 1) {
        if (tid < s) red[tid] += red[tid + s];
        __syncthreads();
    }
    if (tid == 0) partial[bt] = red[0];
    if (wave == 0) atomicAdd(&hist[id], 1);
}

// ---------------------------------------------------------------------------
// K4: finalize loss + perplexity. One block of 256 threads.
// ---------------------------------------------------------------------------
__global__ void finalize_kernel(const float* __restrict__ partial,
                                const int* __restrict__ hist,
                                float* __restrict__ out_scal) {
    __shared__ double red[256];
    const int tid = threadIdx.x;

    double s = 0.0;
    for (int i = tid; i < 512; i += 256) s += (double)partial[i];
    red[tid] = s;
    __syncthreads();
    for (int st = 128; st > 0; st >>= 1) {
        if (tid < st) red[tid] += red[tid + st];
        __syncthreads();
    }
    const double sse = red[0];
    __syncthreads();

    double e = 0.0;
    for (int k = tid; k < NUM_EMBED; k += 256) {
        float p = (float)hist[k] / (float)N_TOK;
        e += (double)(p * logf(p + 1e-10f));
    }
    red[tid] = e;
    __syncthreads();
    for (int st = 128; st > 0; st >>= 1) {
        if (tid < st) red[tid] += red[tid + st];
        __syncthreads();
    }
    if (tid == 0) {
        out_scal[0] = (float)(1.25 * sse / (double)N_ELEM);
        out_scal[1] = expf(-(float)red[0]);
    }
}

// ---------------------------------------------------------------------------
extern "C" void kernel_launch(void* const* d_in, const int* in_sizes, int n_in,
                              void* d_out, int out_size, void* d_ws, size_t ws_size,
                              hipStream_t stream) {
    const float* z   = (const float*)d_in[0];
    const float* emb = (const float*)d_in[1];
    float* o = (float*)d_out;

    // workspace layout (static 6.1 MB; cand sized from ws_size)
    char* ws = (char*)d_ws;
    v8s*  af      = (v8s*)ws;                                        // 4 MB
    v8s*  ef      = (v8s*)(ws + 4194304);                            // 1 MB
    unsigned* tokmax = (unsigned*)(ws + 5242880);                    // 128 KB
    unsigned* cnt    = (unsigned*)(ws + 5373952);                    // 128 KB
    int*   idx     = (int*)(ws + 5505024);                           // 128 KB
    float* invn    = (float*)(ws + 5636096);                         // 32 KB
    float* partial = (float*)(ws + 5668864);                         // 4 KB
    // ---- zeroed region: hist | ovfcnt (contiguous) ----
    int*   hist    = (int*)(ws + 5672960);                           // 32 KB
    unsigned* ovfcnt = (unsigned*)(ws + 5705728);                    // 256 B
    int*   ovflist = (int*)(ws + 5705984);                           // 128 KB
    unsigned long long* cand = (unsigned long long*)(ws + 5837056);

    // candidate slots per token, bounded by remaining workspace (cap 24;
    // expected appends ~7/token with global-prefix thresholds)
    long long avail = (long long)ws_size - 5837056;
    int slots = (int)(avail / ((long long)N_TOK * 8));
    if (slots > 24) slots = 24;
    if (slots < 0)  slots = 0;

    float* out_q      = o;                  // 2097152 floats
    float* out_scal   = o + N_ELEM;         // loss, perplexity
    float* out_idxmap = o + N_ELEM + 2;     // 32768 floats
    float* z_tok      = o;                  // out_q region reused as fp32 token-major
                                            // scratch; overwritten by gather later

    hipMemsetAsync(hist, 0, 5705984 - 5672960, stream);  // hist|ovfcnt

    invnorm_kernel<<<NUM_EMBED / 4, 256, 0, stream>>>(emb, invn);
    en_frag_kernel<<<256, 256, 0, stream>>>(emb, invn, ef);
    z_prep_kernel<<<512, 256, 0, stream>>>(z, z_tok, af);
    pass1f_kernel<<<512, 256, 0, stream>>>(af, ef, tokmax, cnt, cand, slots);
    filter_kernel<<<1024, 256, 0, stream>>>(cand, cnt, tokmax, z_tok, emb, invn,
                                            slots, idx, out_idxmap, ovflist, ovfcnt);
    fallback_kernel<<<512, 256, 0, stream>>>(ovflist, ovfcnt, z_tok, emb, invn,
                                             idx, out_idxmap);
    gather_loss_kernel<<<N_TOK / 64, 256, 0, stream>>>(z, emb, idx, out_q, partial, hist);
    finalize_kernel<<<1, 256, 0, stream>>>(partial, hist, out_scal);
}